// Round 2
// baseline (595.024 us; speedup 1.0000x reference)
//
#include <hip/hip_runtime.h>
#include <hip/hip_bf16.h>

// DRL4Metro pointer-network decode, MI355X persistent-kernel implementation.
// B=8, S=8192, H=128, steps read from d_in[19] (20).
// Grid: 256 blocks x 256 threads; 8 independent groups (one per batch) of 32
// blocks, each group runs its own 20-step loop with a per-group global barrier.
//
// Key numerics: reference computes softmax(attns + 10000.0f) in f32. Adding
// 10000.0f quantizes attn to multiples of 2^-10; argmax returns the FIRST
// index in the top quantized bucket. We replicate the quantization exactly.

#define SS 8192
#define HH 128
#define NB 8

constexpr float kLog2e = 1.4426950408889634f;
constexpr float kLn2   = 0.6931471805599453f;

__device__ __forceinline__ float fsig(float x) {
  return __builtin_amdgcn_rcpf(1.0f + __builtin_amdgcn_exp2f(-x * kLog2e));
}
__device__ __forceinline__ float ftanh(float x) {
  float z = __builtin_amdgcn_exp2f(x * (2.0f * kLog2e));
  return fmaf(-2.0f, __builtin_amdgcn_rcpf(z + 1.0f), 1.0f);
}

// Combine 32 per-block softmax partials (m, argmax-first-idx, sumexp) held by
// lanes 0..31.  All 32 lanes end with the group result.
__device__ __forceinline__ void combine32(const float4* part, int tid,
                                          float& M, int& IX, float& Stot) {
  float4 p = part[tid];
  float m0 = p.x; int ix = __float_as_int(p.y); float s0 = p.z;
  float m = m0;
  #pragma unroll
  for (int k = 1; k < 32; k <<= 1) {
    float om = __shfl_xor(m, k, 32);
    int   oi = __shfl_xor(ix, k, 32);
    if (om > m || (om == m && oi < ix)) { m = om; ix = oi; }
  }
  float term = s0 * __builtin_amdgcn_exp2f((m0 - m) * kLog2e);
  #pragma unroll
  for (int k = 1; k < 32; k <<= 1) term += __shfl_xor(term, k, 32);
  M = m; IX = ix; Stot = term;
}

__global__ __launch_bounds__(256, 1)
void drl4_kernel(const float* __restrict__ g_static,
                 const float* __restrict__ g_dynamic,
                 const float* __restrict__ W_s,  const float* __restrict__ b_s,
                 const float* __restrict__ W_d,  const float* __restrict__ b_d,
                 const float* __restrict__ W_dec,const float* __restrict__ b_dec,
                 const float* __restrict__ W_ih, const float* __restrict__ W_hh,
                 const float* __restrict__ b_ih, const float* __restrict__ b_hh,
                 const float* __restrict__ W_ref,const float* __restrict__ b_ref,
                 const float* __restrict__ W_pd, const float* __restrict__ b_pd,
                 const float* __restrict__ W_q,  const float* __restrict__ b_q,
                 const float* __restrict__ W_att,const int* __restrict__ steps_p,
                 float* __restrict__ out,
                 unsigned* __restrict__ bar,
                 float4* __restrict__ parts,
                 float* __restrict__ hhbuf) {
  const int tid = threadIdx.x;
  const int bid = blockIdx.x;
  const int b   = bid >> 5;   // batch / group id
  const int blk = bid & 31;   // block within group
  const int steps = *steps_p;

  __shared__ float4 s_pack[128];   // {A0,A1,C} pre-scaled by 2*log2e, W_att
  __shared__ float  s_ebias[128];  // W_ref@b_s + b_ref + W_pd@b_d + b_pd + b_q
  __shared__ float  s_gb[512];     // W_ih@b_dec + b_ih + b_hh
  __shared__ float  s_h[128];      // current LSTM hidden (this batch)
  __shared__ float  s_qe[128];     // (q + ebias) * 2*log2e
  __shared__ float  s_scr[256];
  __shared__ float  s_sel[2];      // gathered static coords of chosen city
  __shared__ float  s_wm[4]; __shared__ int s_wi[4]; __shared__ float s_we[4];

  // each thread owns exactly one city of this batch
  const int city = blk * 256 + tid;
  const float sx = g_static[(b * 2 + 0) * SS + city];
  const float sy = g_static[(b * 2 + 1) * SS + city];
  const float dd = g_dynamic[b * SS + city];

  // ---- persistent register fragments (loaded once) -----------------------
  // W_q fragment: thread (g = tid&127, kh = tid>>7) holds row g, half kh.
  const int qg = tid & 127, qkh = tid >> 7;
  float wq[64];
  {
    const float* p = W_q + qg * HH + qkh * 64;
    #pragma unroll
    for (int j = 0; j < 64; j += 4) {
      float4 v = *(const float4*)(p + j);
      wq[j] = v.x; wq[j+1] = v.y; wq[j+2] = v.z; wq[j+3] = v.w;
    }
  }
  // W_hh fragment: block owns gate rows [blk*16, blk*16+16); thread
  // (o = tid&15, kslice = tid>>4) holds 8 weights of row blk*16+o.
  const int ho = tid & 15, hk = tid >> 4;
  const int gout = blk * 16 + ho;
  float whh[8];
  {
    const float* p = W_hh + gout * HH + hk * 8;
    #pragma unroll
    for (int j = 0; j < 8; j += 4) {
      float4 v = *(const float4*)(p + j);
      whh[j] = v.x; whh[j+1] = v.y; whh[j+2] = v.z; whh[j+3] = v.w;
    }
  }

  // ---- one-time per-block precompute (collapsed linear algebra) ----------
  float g1x[4] = {0,0,0,0}, g1y[4] = {0,0,0,0};  // (W_ih@W_dec) rows tid+128j
  if (tid < 128) {
    #pragma unroll
    for (int j = 0; j < 4; ++j) {
      const float* wr = W_ih + (tid + 128 * j) * HH;
      float ax = 0.f, ay = 0.f;
      for (int k = 0; k < HH; ++k) {
        float w = wr[k];
        ax = fmaf(w, W_dec[2 * k],     ax);
        ay = fmaf(w, W_dec[2 * k + 1], ay);
      }
      g1x[j] = ax; g1y[j] = ay;
    }
    float a0 = 0.f, a1 = 0.f, c0 = 0.f, e1 = 0.f, e2 = 0.f;
    const float* wr = W_ref + tid * HH;
    const float* wp = W_pd  + tid * HH;
    for (int k = 0; k < HH; ++k) {
      float w = wr[k], v = wp[k];
      a0 = fmaf(w, W_s[2 * k],     a0);
      a1 = fmaf(w, W_s[2 * k + 1], a1);
      e1 = fmaf(w, b_s[k],         e1);
      c0 = fmaf(v, W_d[k],         c0);
      e2 = fmaf(v, b_d[k],         e2);
    }
    const float sc = 2.0f * kLog2e;   // pre-fold tanh's 2*log2e scaling
    s_pack[tid]  = make_float4(a0 * sc, a1 * sc, c0 * sc, W_att[tid]);
    s_ebias[tid] = e1 + e2 + b_ref[tid] + b_pd[tid] + b_q[tid];
  }
  for (int g = tid; g < 512; g += 256) {
    const float* wr = W_ih + g * HH;
    float acc = b_ih[g] + b_hh[g];
    for (int k = 0; k < HH; ++k) acc = fmaf(wr[k], b_dec[k], acc);
    s_gb[g] = acc;
  }
  float cstate = 0.0f;   // LSTM cell state for (b, tid) — threads tid<128
  __syncthreads();

  unsigned target = 0;
  for (int t = 0; t < steps; ++t) {
    // ---- stage 1: combine previous step's partials → ptr, logp, dec_in ---
    if (t > 0) {
      if (tid < 32) {
        float M, St; int IX;
        combine32(parts + ((t - 1) & 1) * 256 + b * 32, tid, M, IX, St);
        if (tid == 0) {
          s_sel[0] = g_static[(b * 2 + 0) * SS + IX];
          s_sel[1] = g_static[(b * 2 + 1) * SS + IX];
          if (blk == 0) {  // group leader writes outputs for step t-1
            out[b * steps + (t - 1)] = (float)IX;
            out[NB * steps + b * steps + (t - 1)] =
                -__builtin_amdgcn_logf(St) * kLn2;
          }
        }
      }
      __syncthreads();
    }
    // ---- stage 2: LSTM cell (redundant per block; threads tid<128) -------
    if (tid < 128) {
      float gi, gf, gg, go;
      if (t == 0) {   // dec_in = 0, h = 0 → gates are just the bias term
        gi = s_gb[tid];       gf = s_gb[tid + 128];
        gg = s_gb[tid + 256]; go = s_gb[tid + 384];
      } else {
        const float selx = s_sel[0], sely = s_sel[1];
        const float* hp = hhbuf + (t & 1) * 4096 + b * 512;  // h@W_hh.T
        gi = fmaf(selx, g1x[0], fmaf(sely, g1y[0], s_gb[tid]       + hp[tid]));
        gf = fmaf(selx, g1x[1], fmaf(sely, g1y[1], s_gb[tid + 128] + hp[tid + 128]));
        gg = fmaf(selx, g1x[2], fmaf(sely, g1y[2], s_gb[tid + 256] + hp[tid + 256]));
        go = fmaf(selx, g1x[3], fmaf(sely, g1y[3], s_gb[tid + 384] + hp[tid + 384]));
      }
      cstate  = fmaf(fsig(gf), cstate, fsig(gi) * ftanh(gg));
      s_h[tid] = fsig(go) * ftanh(cstate);
    }
    __syncthreads();
    // ---- stage 2b: q = h @ W_q.T from register fragments (split-K by 2) --
    {
      const float* hs = s_h + qkh * 64;
      float qa = 0.f;
      #pragma unroll
      for (int u = 0; u < 64; ++u) qa = fmaf(wq[u], hs[u], qa);
      s_scr[tid] = qa;
    }
    __syncthreads();
    if (tid < 128)
      s_qe[tid] = (s_scr[tid] + s_scr[tid + 128] + s_ebias[tid]) * (2.0f * kLog2e);
    __syncthreads();
    // ---- stage 3: next step's h @ W_hh.T slice (split across blocks) -----
    {
      const float* hs = s_h + hk * 8;
      float pa = 0.f;
      #pragma unroll
      for (int u = 0; u < 8; ++u) pa = fmaf(whh[u], hs[u], pa);
      s_scr[tid] = pa;
    }
    __syncthreads();
    if (tid < 16) {
      float acc = 0.f;
      #pragma unroll
      for (int j = 0; j < 16; ++j) acc += s_scr[j * 16 + tid];
      hhbuf[((t + 1) & 1) * 4096 + b * 512 + blk * 16 + tid] = acc;
    }
    // ---- stage 4: attention over this block's 256 cities -----------------
    float acc[4] = {0.f, 0.f, 0.f, 0.f};
    #pragma unroll 8
    for (int h = 0; h < 128; ++h) {
      float4 p = s_pack[h];
      float tt = fmaf(p.x, sx, fmaf(p.y, sy, fmaf(p.z, dd, s_qe[h])));
      float z  = __builtin_amdgcn_exp2f(tt);                        // e^{2x}
      float th = fmaf(-2.0f, __builtin_amdgcn_rcpf(z + 1.0f), 1.0f); // tanh
      acc[h & 3] = fmaf(p.w, th, acc[h & 3]);
    }
    float a = (acc[0] + acc[1]) + (acc[2] + acc[3]);
    // Replicate reference f32 semantics: attns + 10000.0f quantizes to
    // multiples of 2^-10. Argmax/ties/sumexp all operate on the quantized
    // value (first-index tie-break == np.argmax).
    a = a + 10000.0f;
    // block reduce: max + first-argmax
    float m = a; int ix = city;
    #pragma unroll
    for (int k = 1; k < 64; k <<= 1) {
      float om = __shfl_xor(m, k);
      int   oi = __shfl_xor(ix, k);
      if (om > m || (om == m && oi < ix)) { m = om; ix = oi; }
    }
    const int wv = tid >> 6;
    if ((tid & 63) == 0) { s_wm[wv] = m; s_wi[wv] = ix; }
    __syncthreads();
    m = s_wm[0]; ix = s_wi[0];
    #pragma unroll
    for (int w = 1; w < 4; ++w) {
      float om = s_wm[w]; int oi = s_wi[w];
      if (om > m || (om == m && oi < ix)) { m = om; ix = oi; }
    }
    float ee = __builtin_amdgcn_exp2f((a - m) * kLog2e);  // a-m exact (Sterbenz)
    #pragma unroll
    for (int k = 1; k < 64; k <<= 1) ee += __shfl_xor(ee, k);
    if ((tid & 63) == 0) s_we[wv] = ee;
    __syncthreads();
    if (tid == 0) {
      float St = (s_we[0] + s_we[1]) + (s_we[2] + s_we[3]);
      parts[(t & 1) * 256 + b * 32 + blk] =
          make_float4(m, __int_as_float(ix), St, 0.0f);
    }
    // ---- per-group barrier (monotonic counter, device-scope) -------------
    __threadfence();        // release: publish hhbuf/parts/out writes
    __syncthreads();
    target += 32;
    if (tid == 0) {
      atomicAdd(&bar[b * 16], 1u);
      while (atomicAdd(&bar[b * 16], 0u) < target) __builtin_amdgcn_s_sleep(1);
      __threadfence();      // acquire: invalidate stale L1/L2
    }
    __syncthreads();
  }
  // epilogue: outputs of the final step
  if (blk == 0 && tid < 32) {
    float M, St; int IX;
    combine32(parts + ((steps - 1) & 1) * 256 + b * 32, tid, M, IX, St);
    if (tid == 0) {
      out[b * steps + (steps - 1)] = (float)IX;
      out[NB * steps + b * steps + (steps - 1)] =
          -__builtin_amdgcn_logf(St) * kLn2;
    }
  }
}

extern "C" void kernel_launch(void* const* d_in, const int* in_sizes, int n_in,
                              void* d_out, int out_size, void* d_ws, size_t ws_size,
                              hipStream_t stream) {
  // ws layout: [0,512) barrier counters (zeroed each launch; d_ws is poisoned),
  //            [4096, 4096+8192) softmax partials (double-buffered float4),
  //            [12288, 12288+32768) h@W_hh.T buffers (double-buffered).
  hipMemsetAsync(d_ws, 0, 512, stream);
  unsigned* bar   = (unsigned*)d_ws;
  float4*   parts = (float4*)((char*)d_ws + 4096);
  float*    hhb   = (float*)((char*)d_ws + 12288);
  drl4_kernel<<<dim3(256), dim3(256), 0, stream>>>(
      (const float*)d_in[0],  (const float*)d_in[1],
      (const float*)d_in[2],  (const float*)d_in[3],
      (const float*)d_in[4],  (const float*)d_in[5],
      (const float*)d_in[6],  (const float*)d_in[7],
      (const float*)d_in[8],  (const float*)d_in[9],
      (const float*)d_in[10], (const float*)d_in[11],
      (const float*)d_in[12], (const float*)d_in[13],
      (const float*)d_in[14], (const float*)d_in[15],
      (const float*)d_in[16], (const float*)d_in[17],
      (const float*)d_in[18], (const int*)d_in[19],
      (float*)d_out, bar, parts, hhb);
}

// Round 3
// 293.650 us; speedup vs baseline: 2.0263x; 2.0263x over previous
//
#include <hip/hip_runtime.h>
#include <hip/hip_bf16.h>

// DRL4Metro pointer-network decode, MI355X persistent-kernel implementation.
// B=8, S=8192, H=128, steps read from d_in[19] (20).
// Grid: 256 blocks x 256 threads; 8 independent groups (one per batch) of 32
// blocks, each group runs its own 20-step loop with a per-group global barrier.
//
// Numerics: reference computes softmax(attns + 10000.0f) in f32. Adding
// 10000.0f quantizes attn to multiples of 2^-10; argmax returns the FIRST
// index in the top quantized bucket. We replicate the quantization exactly.
//
// Sync design (R3): NO __threadfence (agent fences emit buffer_wbl2/buffer_inv
// = full L2 writeback+invalidate per wave — measured ~23us/step in R2).
// All cross-block data uses relaxed agent-scope coherent loads/stores
// (sc0 sc1, bypass non-coherent per-XCD L2). Barrier: leader-only
// s_waitcnt vmcnt(0) + relaxed fetch_add; spinners poll with coherent LOADS
// (no RMW storm).

#define SS 8192
#define HH 128
#define NB 8

constexpr float kLog2e = 1.4426950408889634f;
constexpr float kLn2   = 0.6931471805599453f;

__device__ __forceinline__ float fsig(float x) {
  return __builtin_amdgcn_rcpf(1.0f + __builtin_amdgcn_exp2f(-x * kLog2e));
}
__device__ __forceinline__ float ftanh(float x) {
  float z = __builtin_amdgcn_exp2f(x * (2.0f * kLog2e));
  return fmaf(-2.0f, __builtin_amdgcn_rcpf(z + 1.0f), 1.0f);
}

// Device-coherent (agent-scope, sc0 sc1) accessors — bypass per-XCD L2.
__device__ __forceinline__ float cld(const float* p) {
  return __hip_atomic_load(p, __ATOMIC_RELAXED, __HIP_MEMORY_SCOPE_AGENT);
}
__device__ __forceinline__ void cst(float* p, float v) {
  __hip_atomic_store(p, v, __ATOMIC_RELAXED, __HIP_MEMORY_SCOPE_AGENT);
}

// Combine 32 per-block softmax partials (m, argmax-first-idx, sumexp) held by
// lanes 0..31 (coherent reads).  All 32 lanes end with the group result.
__device__ __forceinline__ void combine32(const float* part, int tid,
                                          float& M, int& IX, float& Stot) {
  const float* p = part + tid * 4;
  float m0 = cld(p + 0);
  int   ix = __float_as_int(cld(p + 1));
  float s0 = cld(p + 2);
  float m = m0;
  #pragma unroll
  for (int k = 1; k < 32; k <<= 1) {
    float om = __shfl_xor(m, k, 32);
    int   oi = __shfl_xor(ix, k, 32);
    if (om > m || (om == m && oi < ix)) { m = om; ix = oi; }
  }
  float term = s0 * __builtin_amdgcn_exp2f((m0 - m) * kLog2e);
  #pragma unroll
  for (int k = 1; k < 32; k <<= 1) term += __shfl_xor(term, k, 32);
  M = m; IX = ix; Stot = term;
}

__global__ __launch_bounds__(256, 1)
void drl4_kernel(const float* __restrict__ g_static,
                 const float* __restrict__ g_dynamic,
                 const float* __restrict__ W_s,  const float* __restrict__ b_s,
                 const float* __restrict__ W_d,  const float* __restrict__ b_d,
                 const float* __restrict__ W_dec,const float* __restrict__ b_dec,
                 const float* __restrict__ W_ih, const float* __restrict__ W_hh,
                 const float* __restrict__ b_ih, const float* __restrict__ b_hh,
                 const float* __restrict__ W_ref,const float* __restrict__ b_ref,
                 const float* __restrict__ W_pd, const float* __restrict__ b_pd,
                 const float* __restrict__ W_q,  const float* __restrict__ b_q,
                 const float* __restrict__ W_att,const int* __restrict__ steps_p,
                 float* __restrict__ out,
                 unsigned* __restrict__ bar,
                 float* __restrict__ parts,
                 float* __restrict__ hhbuf) {
  const int tid = threadIdx.x;
  const int bid = blockIdx.x;
  const int b   = bid >> 5;   // batch / group id
  const int blk = bid & 31;   // block within group
  const int steps = *steps_p;

  __shared__ float4 s_pack[128];   // {A0,A1,C} pre-scaled by 2*log2e, W_att
  __shared__ float  s_ebias[128];  // W_ref@b_s + b_ref + W_pd@b_d + b_pd + b_q
  __shared__ float  s_gb[512];     // W_ih@b_dec + b_ih + b_hh
  __shared__ float  s_h[128];      // current LSTM hidden (this batch)
  __shared__ float  s_qe[128];     // (q + ebias) * 2*log2e
  __shared__ float  s_scr[256];
  __shared__ float  s_sel[2];      // gathered static coords of chosen city
  __shared__ float  s_wm[4]; __shared__ int s_wi[4]; __shared__ float s_we[4];

  // each thread owns exactly one city of this batch
  const int city = blk * 256 + tid;
  const float sx = g_static[(b * 2 + 0) * SS + city];
  const float sy = g_static[(b * 2 + 1) * SS + city];
  const float dd = g_dynamic[b * SS + city];

  // ---- persistent register fragments (loaded once) -----------------------
  // W_q fragment: thread (g = tid&127, kh = tid>>7) holds row g, half kh.
  const int qg = tid & 127, qkh = tid >> 7;
  float wq[64];
  {
    const float* p = W_q + qg * HH + qkh * 64;
    #pragma unroll
    for (int j = 0; j < 64; j += 4) {
      float4 v = *(const float4*)(p + j);
      wq[j] = v.x; wq[j+1] = v.y; wq[j+2] = v.z; wq[j+3] = v.w;
    }
  }
  // W_hh fragment: block owns gate rows [blk*16, blk*16+16); thread
  // (o = tid&15, kslice = tid>>4) holds 8 weights of row blk*16+o.
  const int ho = tid & 15, hk = tid >> 4;
  const int gout = blk * 16 + ho;
  float whh[8];
  {
    const float* p = W_hh + gout * HH + hk * 8;
    #pragma unroll
    for (int j = 0; j < 8; j += 4) {
      float4 v = *(const float4*)(p + j);
      whh[j] = v.x; whh[j+1] = v.y; whh[j+2] = v.z; whh[j+3] = v.w;
    }
  }

  // ---- one-time per-block precompute (collapsed linear algebra) ----------
  float g1x[4] = {0,0,0,0}, g1y[4] = {0,0,0,0};  // (W_ih@W_dec) rows tid+128j
  if (tid < 128) {
    #pragma unroll
    for (int j = 0; j < 4; ++j) {
      const float* wr = W_ih + (tid + 128 * j) * HH;
      float ax = 0.f, ay = 0.f;
      for (int k = 0; k < HH; ++k) {
        float w = wr[k];
        ax = fmaf(w, W_dec[2 * k],     ax);
        ay = fmaf(w, W_dec[2 * k + 1], ay);
      }
      g1x[j] = ax; g1y[j] = ay;
    }
    float a0 = 0.f, a1 = 0.f, c0 = 0.f, e1 = 0.f, e2 = 0.f;
    const float* wr = W_ref + tid * HH;
    const float* wp = W_pd  + tid * HH;
    for (int k = 0; k < HH; ++k) {
      float w = wr[k], v = wp[k];
      a0 = fmaf(w, W_s[2 * k],     a0);
      a1 = fmaf(w, W_s[2 * k + 1], a1);
      e1 = fmaf(w, b_s[k],         e1);
      c0 = fmaf(v, W_d[k],         c0);
      e2 = fmaf(v, b_d[k],         e2);
    }
    const float sc = 2.0f * kLog2e;   // pre-fold tanh's 2*log2e scaling
    s_pack[tid]  = make_float4(a0 * sc, a1 * sc, c0 * sc, W_att[tid]);
    s_ebias[tid] = e1 + e2 + b_ref[tid] + b_pd[tid] + b_q[tid];
  }
  for (int g = tid; g < 512; g += 256) {
    const float* wr = W_ih + g * HH;
    float acc = b_ih[g] + b_hh[g];
    for (int k = 0; k < HH; ++k) acc = fmaf(wr[k], b_dec[k], acc);
    s_gb[g] = acc;
  }
  float cstate = 0.0f;   // LSTM cell state for (b, tid) — threads tid<128
  __syncthreads();

  unsigned target = 0;
  for (int t = 0; t < steps; ++t) {
    // ---- stage 1: combine previous step's partials → ptr, logp, dec_in ---
    float hp0 = 0.f, hp1 = 0.f, hp2 = 0.f, hp3 = 0.f;
    if (t > 0) {
      // pre-issue coherent hhbuf loads; latency overlaps the combine below
      if (tid < 128) {
        const float* hp = hhbuf + (t & 1) * 4096 + b * 512 + tid;
        hp0 = cld(hp);       hp1 = cld(hp + 128);
        hp2 = cld(hp + 256); hp3 = cld(hp + 384);
      }
      if (tid < 32) {
        float M, St; int IX;
        combine32(parts + ((t - 1) & 1) * 1024 + b * 128, tid, M, IX, St);
        if (tid == 0) {
          s_sel[0] = g_static[(b * 2 + 0) * SS + IX];
          s_sel[1] = g_static[(b * 2 + 1) * SS + IX];
          if (blk == 0) {  // group leader writes outputs for step t-1
            out[b * steps + (t - 1)] = (float)IX;
            out[NB * steps + b * steps + (t - 1)] =
                -__builtin_amdgcn_logf(St) * kLn2;
          }
        }
      }
      __syncthreads();
    }
    // ---- stage 2: LSTM cell (redundant per block; threads tid<128) -------
    if (tid < 128) {
      float gi, gf, gg, go;
      if (t == 0) {   // dec_in = 0, h = 0 → gates are just the bias term
        gi = s_gb[tid];       gf = s_gb[tid + 128];
        gg = s_gb[tid + 256]; go = s_gb[tid + 384];
      } else {
        const float selx = s_sel[0], sely = s_sel[1];
        gi = fmaf(selx, g1x[0], fmaf(sely, g1y[0], s_gb[tid]       + hp0));
        gf = fmaf(selx, g1x[1], fmaf(sely, g1y[1], s_gb[tid + 128] + hp1));
        gg = fmaf(selx, g1x[2], fmaf(sely, g1y[2], s_gb[tid + 256] + hp2));
        go = fmaf(selx, g1x[3], fmaf(sely, g1y[3], s_gb[tid + 384] + hp3));
      }
      cstate  = fmaf(fsig(gf), cstate, fsig(gi) * ftanh(gg));
      s_h[tid] = fsig(go) * ftanh(cstate);
    }
    __syncthreads();
    // ---- stage 2b: q = h @ W_q.T from register fragments (split-K by 2) --
    {
      const float* hs = s_h + qkh * 64;
      float qa = 0.f;
      #pragma unroll
      for (int u = 0; u < 64; ++u) qa = fmaf(wq[u], hs[u], qa);
      s_scr[tid] = qa;
    }
    __syncthreads();
    if (tid < 128)
      s_qe[tid] = (s_scr[tid] + s_scr[tid + 128] + s_ebias[tid]) * (2.0f * kLog2e);
    __syncthreads();
    // ---- stage 3: next step's h @ W_hh.T slice (split across blocks) -----
    {
      const float* hs = s_h + hk * 8;
      float pa = 0.f;
      #pragma unroll
      for (int u = 0; u < 8; ++u) pa = fmaf(whh[u], hs[u], pa);
      s_scr[tid] = pa;
    }
    __syncthreads();
    if (tid < 16) {
      float acc = 0.f;
      #pragma unroll
      for (int j = 0; j < 16; ++j) acc += s_scr[j * 16 + tid];
      cst(hhbuf + ((t + 1) & 1) * 4096 + b * 512 + blk * 16 + tid, acc);
    }
    // ---- stage 4: attention over this block's 256 cities -----------------
    float acc[4] = {0.f, 0.f, 0.f, 0.f};
    #pragma unroll 8
    for (int h = 0; h < 128; ++h) {
      float4 p = s_pack[h];
      float tt = fmaf(p.x, sx, fmaf(p.y, sy, fmaf(p.z, dd, s_qe[h])));
      float z  = __builtin_amdgcn_exp2f(tt);                        // e^{2x}
      float th = fmaf(-2.0f, __builtin_amdgcn_rcpf(z + 1.0f), 1.0f); // tanh
      acc[h & 3] = fmaf(p.w, th, acc[h & 3]);
    }
    float a = (acc[0] + acc[1]) + (acc[2] + acc[3]);
    // Replicate reference f32 semantics: attns + 10000.0f quantizes to
    // multiples of 2^-10. Argmax/ties/sumexp all operate on the quantized
    // value (first-index tie-break == np.argmax).
    a = a + 10000.0f;
    // block reduce: max + first-argmax
    float m = a; int ix = city;
    #pragma unroll
    for (int k = 1; k < 64; k <<= 1) {
      float om = __shfl_xor(m, k);
      int   oi = __shfl_xor(ix, k);
      if (om > m || (om == m && oi < ix)) { m = om; ix = oi; }
    }
    const int wv = tid >> 6;
    if ((tid & 63) == 0) { s_wm[wv] = m; s_wi[wv] = ix; }
    __syncthreads();
    m = s_wm[0]; ix = s_wi[0];
    #pragma unroll
    for (int w = 1; w < 4; ++w) {
      float om = s_wm[w]; int oi = s_wi[w];
      if (om > m || (om == m && oi < ix)) { m = om; ix = oi; }
    }
    float ee = __builtin_amdgcn_exp2f((a - m) * kLog2e);  // a-m exact (Sterbenz)
    #pragma unroll
    for (int k = 1; k < 64; k <<= 1) ee += __shfl_xor(ee, k);
    if ((tid & 63) == 0) s_we[wv] = ee;
    __syncthreads();
    if (tid == 0) {
      float St = (s_we[0] + s_we[1]) + (s_we[2] + s_we[3]);
      float* p = parts + (t & 1) * 1024 + b * 128 + blk * 4;
      cst(p + 0, m);
      cst(p + 1, __int_as_float(ix));
      cst(p + 2, St);
    }
    // ---- per-group barrier (leader-only, coherent, no cache flushes) -----
    __syncthreads();
    target += 32;
    if (tid == 0) {
      // order wave-0's coherent stores (hhbuf, parts) before the signal;
      // all barrier-crossing global stores are issued by wave 0.
      asm volatile("s_waitcnt vmcnt(0)" ::: "memory");
      __hip_atomic_fetch_add(&bar[b * 16], 1u, __ATOMIC_RELAXED,
                             __HIP_MEMORY_SCOPE_AGENT);
      while (__hip_atomic_load(&bar[b * 16], __ATOMIC_RELAXED,
                               __HIP_MEMORY_SCOPE_AGENT) < target)
        __builtin_amdgcn_s_sleep(1);
    }
    __syncthreads();
  }
  // epilogue: outputs of the final step
  if (blk == 0 && tid < 32) {
    float M, St; int IX;
    combine32(parts + ((steps - 1) & 1) * 1024 + b * 128, tid, M, IX, St);
    if (tid == 0) {
      out[b * steps + (steps - 1)] = (float)IX;
      out[NB * steps + b * steps + (steps - 1)] =
          -__builtin_amdgcn_logf(St) * kLn2;
    }
  }
}

extern "C" void kernel_launch(void* const* d_in, const int* in_sizes, int n_in,
                              void* d_out, int out_size, void* d_ws, size_t ws_size,
                              hipStream_t stream) {
  // ws layout: [0,512) barrier counters (zeroed each launch),
  //            [4096, 4096+8192) softmax partials (double-buffered, 16B/slot),
  //            [12288, 12288+32768) h@W_hh.T buffers (double-buffered).
  hipMemsetAsync(d_ws, 0, 512, stream);
  unsigned* bar   = (unsigned*)d_ws;
  float*    parts = (float*)((char*)d_ws + 4096);
  float*    hhb   = (float*)((char*)d_ws + 12288);
  drl4_kernel<<<dim3(256), dim3(256), 0, stream>>>(
      (const float*)d_in[0],  (const float*)d_in[1],
      (const float*)d_in[2],  (const float*)d_in[3],
      (const float*)d_in[4],  (const float*)d_in[5],
      (const float*)d_in[6],  (const float*)d_in[7],
      (const float*)d_in[8],  (const float*)d_in[9],
      (const float*)d_in[10], (const float*)d_in[11],
      (const float*)d_in[12], (const float*)d_in[13],
      (const float*)d_in[14], (const float*)d_in[15],
      (const float*)d_in[16], (const float*)d_in[17],
      (const float*)d_in[18], (const int*)d_in[19],
      (float*)d_out, bar, parts, hhb);
}

// Round 4
// 256.550 us; speedup vs baseline: 2.3193x; 1.1446x over previous
//
#include <hip/hip_runtime.h>
#include <hip/hip_bf16.h>

// DRL4Metro pointer-network decode, MI355X persistent-kernel implementation.
// B=8, S=8192, H=128, steps read from d_in[19] (20).
// Grid: 256 blocks x 256 threads; 8 groups (one per batch) of 32 blocks.
//
// R4 changes vs R3 (211us):
//  - barrier counters / parts / hhbuf slots padded to 4KB (kill IC false
//    sharing across the 8 groups' agent-scope atomics)
//  - attention: per-thread step-invariant zb[h]=exp2(A0sx+A1sy+Cdd) and
//    watt[h] in VGPRs (~360 VGPRs, legal at 1 wave/SIMD); stage2b publishes
//    exp2(qe) so the inner loop is z=zb*zq, rcp, 2 fma (4 VALU + 1 trans,
//    no pack LDS reads)
//  - q-combine via shfl_xor(32) (one LDS round + one __syncthreads removed)
//  - parts slot carries the block winner's (sx,sy) -> no dependent gather
//  - stage 3 (h@W_hh) moved after attention, overlapped with reduce syncs
//
// Numerics: softmax(attns + 10000.0f) in f32 quantizes attn to 2^-10 buckets;
// argmax = first index in top bucket. We add 10000.0f before the reduce and
// keep tanh/accumulation arithmetic identical to the R3 passing kernel.

#define SS 8192
#define HH 128
#define NB 8

constexpr float kLog2e = 1.4426950408889634f;
constexpr float kLn2   = 0.6931471805599453f;

__device__ __forceinline__ float fsig(float x) {
  return __builtin_amdgcn_rcpf(1.0f + __builtin_amdgcn_exp2f(-x * kLog2e));
}
__device__ __forceinline__ float ftanh(float x) {
  float z = __builtin_amdgcn_exp2f(x * (2.0f * kLog2e));
  return fmaf(-2.0f, __builtin_amdgcn_rcpf(z + 1.0f), 1.0f);
}

// Device-coherent (agent-scope, sc0 sc1) accessors — bypass per-XCD L2.
__device__ __forceinline__ float cld(const float* p) {
  return __hip_atomic_load(p, __ATOMIC_RELAXED, __HIP_MEMORY_SCOPE_AGENT);
}
__device__ __forceinline__ unsigned long long cld64(const void* p) {
  return __hip_atomic_load((const unsigned long long*)p, __ATOMIC_RELAXED,
                           __HIP_MEMORY_SCOPE_AGENT);
}
__device__ __forceinline__ void cst(float* p, float v) {
  __hip_atomic_store(p, v, __ATOMIC_RELAXED, __HIP_MEMORY_SCOPE_AGENT);
}

// Combine 32 per-block partials {m, ix, S, selx, sely} (8-float slots) held
// by lanes 0..31. All lanes end with group result + winning block's coords.
__device__ __forceinline__ void combine32(const float* part, int tid,
                                          float& M, int& IX, float& Stot,
                                          float& SelX, float& SelY) {
  const float* p = part + tid * 8;
  unsigned long long q0 = cld64(p);          // [m, ix]
  unsigned long long q1 = cld64(p + 2);      // [S, sx]
  float sy0 = cld(p + 4);
  float m0  = __uint_as_float((unsigned)q0);
  int   ix0 = (int)(unsigned)(q0 >> 32);
  float s0  = __uint_as_float((unsigned)q1);
  float sx0 = __uint_as_float((unsigned)(q1 >> 32));
  float m = m0; int ix = ix0;
  #pragma unroll
  for (int k = 1; k < 32; k <<= 1) {
    float om = __shfl_xor(m, k, 32);
    int   oi = __shfl_xor(ix, k, 32);
    if (om > m || (om == m && oi < ix)) { m = om; ix = oi; }
  }
  float term = s0 * __builtin_amdgcn_exp2f((m0 - m) * kLog2e);
  #pragma unroll
  for (int k = 1; k < 32; k <<= 1) term += __shfl_xor(term, k, 32);
  // winner block's coords: exactly one lane has ix0 == ix (city ids unique)
  unsigned long long mk = __ballot(ix0 == ix);
  int src = __ffsll(mk) - 1;
  SelX = __shfl(sx0, src);
  SelY = __shfl(sy0, src);
  M = m; IX = ix; Stot = term;
}

__global__ __launch_bounds__(256, 1)
void drl4_kernel(const float* __restrict__ g_static,
                 const float* __restrict__ g_dynamic,
                 const float* __restrict__ W_s,  const float* __restrict__ b_s,
                 const float* __restrict__ W_d,  const float* __restrict__ b_d,
                 const float* __restrict__ W_dec,const float* __restrict__ b_dec,
                 const float* __restrict__ W_ih, const float* __restrict__ W_hh,
                 const float* __restrict__ b_ih, const float* __restrict__ b_hh,
                 const float* __restrict__ W_ref,const float* __restrict__ b_ref,
                 const float* __restrict__ W_pd, const float* __restrict__ b_pd,
                 const float* __restrict__ W_q,  const float* __restrict__ b_q,
                 const float* __restrict__ W_att,const int* __restrict__ steps_p,
                 float* __restrict__ out,
                 unsigned* __restrict__ bar,
                 float* __restrict__ parts,
                 float* __restrict__ hhbuf) {
  const int tid = threadIdx.x;
  const int bid = blockIdx.x;
  const int b   = bid >> 5;   // batch / group id
  const int blk = bid & 31;   // block within group
  const int steps = *steps_p;

  __shared__ float4 s_pack[128];   // startup only: {A0,A1,C}*2log2e, W_att
  __shared__ float  s_ebias[128];  // W_ref@b_s + b_ref + W_pd@b_d + b_pd + b_q
  __shared__ float  s_gb[512];     // W_ih@b_dec + b_ih + b_hh
  __shared__ float  s_h[128];      // current LSTM hidden (this batch)
  __shared__ __align__(16) float s_qe[128];  // exp2((q+ebias)*2log2e)
  __shared__ float  s_scr[256];
  __shared__ float  s_sel[2];      // chosen city coords (prev step)
  __shared__ float  s_wsel[2];     // this block's local winner coords
  __shared__ float  s_wm[4]; __shared__ int s_wi[4]; __shared__ float s_we[4];

  // each thread owns exactly one city of this batch
  const int city = blk * 256 + tid;
  const float sx = g_static[(b * 2 + 0) * SS + city];
  const float sy = g_static[(b * 2 + 1) * SS + city];
  const float dd = g_dynamic[b * SS + city];

  // ---- persistent register fragments (loaded once) -----------------------
  // W_q: wave w, lane l -> row = w*32 + (l&31), half = l>>5 (shfl_xor(32)
  // combines halves in-wave).
  const int qrow  = (tid >> 6) * 32 + (tid & 31);
  const int qhalf = (tid >> 5) & 1;
  float wq[64];
  {
    const float* p = W_q + qrow * HH + qhalf * 64;
    #pragma unroll
    for (int j = 0; j < 64; j += 4) {
      float4 v = *(const float4*)(p + j);
      wq[j] = v.x; wq[j+1] = v.y; wq[j+2] = v.z; wq[j+3] = v.w;
    }
  }
  // W_hh fragment: block owns gate rows [blk*16, blk*16+16).
  const int ho = tid & 15, hk = tid >> 4;
  float whh[8];
  {
    const float* p = W_hh + (blk * 16 + ho) * HH + hk * 8;
    #pragma unroll
    for (int j = 0; j < 8; j += 4) {
      float4 v = *(const float4*)(p + j);
      whh[j] = v.x; whh[j+1] = v.y; whh[j+2] = v.z; whh[j+3] = v.w;
    }
  }

  // ---- one-time per-block precompute (collapsed linear algebra) ----------
  float g1x[4] = {0,0,0,0}, g1y[4] = {0,0,0,0};  // (W_ih@W_dec) rows tid+128j
  if (tid < 128) {
    #pragma unroll
    for (int j = 0; j < 4; ++j) {
      const float* wr = W_ih + (tid + 128 * j) * HH;
      float ax = 0.f, ay = 0.f;
      for (int k = 0; k < HH; ++k) {
        float w = wr[k];
        ax = fmaf(w, W_dec[2 * k],     ax);
        ay = fmaf(w, W_dec[2 * k + 1], ay);
      }
      g1x[j] = ax; g1y[j] = ay;
    }
    float a0 = 0.f, a1 = 0.f, c0 = 0.f, e1 = 0.f, e2 = 0.f;
    const float* wr = W_ref + tid * HH;
    const float* wp = W_pd  + tid * HH;
    for (int k = 0; k < HH; ++k) {
      float w = wr[k], v = wp[k];
      a0 = fmaf(w, W_s[2 * k],     a0);
      a1 = fmaf(w, W_s[2 * k + 1], a1);
      e1 = fmaf(w, b_s[k],         e1);
      c0 = fmaf(v, W_d[k],         c0);
      e2 = fmaf(v, b_d[k],         e2);
    }
    const float sc = 2.0f * kLog2e;   // pre-fold tanh's 2*log2e scaling
    s_pack[tid]  = make_float4(a0 * sc, a1 * sc, c0 * sc, W_att[tid]);
    s_ebias[tid] = e1 + e2 + b_ref[tid] + b_pd[tid] + b_q[tid];
  }
  for (int g = tid; g < 512; g += 256) {
    const float* wr = W_ih + g * HH;
    float acc = b_ih[g] + b_hh[g];
    for (int k = 0; k < HH; ++k) acc = fmaf(wr[k], b_dec[k], acc);
    s_gb[g] = acc;
  }
  float cstate = 0.0f;   // LSTM cell state for (b, tid) — threads tid<128
  __syncthreads();

  // ---- per-thread step-invariant attention state (VGPR arrays) -----------
  // zb[h] = exp2((A0*sx + A1*sy + C*dd)*2log2e); watt[h] = W_att[h]
  float zb[128], watt[128];
  #pragma unroll
  for (int h = 0; h < 128; ++h) {
    float4 p = s_pack[h];
    zb[h]   = __builtin_amdgcn_exp2f(fmaf(p.x, sx, fmaf(p.y, sy, p.z * dd)));
    watt[h] = p.w;
  }

  unsigned target = 0;
  for (int t = 0; t < steps; ++t) {
    // ---- stage 1: combine previous step's partials → ptr, logp, dec_in ---
    float hp0 = 0.f, hp1 = 0.f, hp2 = 0.f, hp3 = 0.f;
    if (t > 0) {
      // pre-issue coherent hhbuf loads; latency overlaps the combine below
      if (tid < 128) {
        const float* hp = hhbuf + ((t & 1) * 8 + b) * 1024 + tid;
        hp0 = cld(hp);       hp1 = cld(hp + 128);
        hp2 = cld(hp + 256); hp3 = cld(hp + 384);
      }
      if (tid < 32) {
        float M, St, sxw, syw; int IX;
        combine32(parts + ((t - 1) & 1) * 2048 + b * 256, tid, M, IX, St,
                  sxw, syw);
        if (tid == 0) {
          s_sel[0] = sxw; s_sel[1] = syw;
          if (blk == 0) {  // group leader writes outputs for step t-1
            out[b * steps + (t - 1)] = (float)IX;
            out[NB * steps + b * steps + (t - 1)] =
                -__builtin_amdgcn_logf(St) * kLn2;
          }
        }
      }
      __syncthreads();
    }
    // ---- stage 2: LSTM cell (redundant per block; threads tid<128) -------
    if (tid < 128) {
      float gi, gf, gg, go;
      if (t == 0) {   // dec_in = 0, h = 0 → gates are just the bias term
        gi = s_gb[tid];       gf = s_gb[tid + 128];
        gg = s_gb[tid + 256]; go = s_gb[tid + 384];
      } else {
        const float selx = s_sel[0], sely = s_sel[1];
        gi = fmaf(selx, g1x[0], fmaf(sely, g1y[0], s_gb[tid]       + hp0));
        gf = fmaf(selx, g1x[1], fmaf(sely, g1y[1], s_gb[tid + 128] + hp1));
        gg = fmaf(selx, g1x[2], fmaf(sely, g1y[2], s_gb[tid + 256] + hp2));
        go = fmaf(selx, g1x[3], fmaf(sely, g1y[3], s_gb[tid + 384] + hp3));
      }
      cstate  = fmaf(fsig(gf), cstate, fsig(gi) * ftanh(gg));
      s_h[tid] = fsig(go) * ftanh(cstate);
    }
    __syncthreads();
    // ---- stage 2b: q = h @ W_q.T; halves combined in-wave via shfl -------
    {
      const float* hs = s_h + (qhalf << 6);
      float qa = 0.f;
      #pragma unroll
      for (int u = 0; u < 64; ++u) qa = fmaf(wq[u], hs[u], qa);
      float qo = __shfl_xor(qa, 32);
      if (qhalf == 0) {   // lanes 0..31: qa(half0) + qo(half1), same order as R3
        float qe = (qa + qo + s_ebias[qrow]) * (2.0f * kLog2e);
        s_qe[qrow] = __builtin_amdgcn_exp2f(qe);
      }
    }
    __syncthreads();
    // ---- stage 4: attention, z = zb*zq; th = 1 - 2/(z+1) -----------------
    float a0 = 0.f, a1 = 0.f, a2 = 0.f, a3 = 0.f;
    #pragma unroll
    for (int h = 0; h < 128; h += 4) {
      float4 zq = *(const float4*)(s_qe + h);
      float z0 = zb[h+0] * zq.x, z1 = zb[h+1] * zq.y;
      float z2 = zb[h+2] * zq.z, z3 = zb[h+3] * zq.w;
      float r0 = __builtin_amdgcn_rcpf(z0 + 1.0f);
      float r1 = __builtin_amdgcn_rcpf(z1 + 1.0f);
      float r2 = __builtin_amdgcn_rcpf(z2 + 1.0f);
      float r3 = __builtin_amdgcn_rcpf(z3 + 1.0f);
      a0 = fmaf(watt[h+0], fmaf(-2.0f, r0, 1.0f), a0);
      a1 = fmaf(watt[h+1], fmaf(-2.0f, r1, 1.0f), a1);
      a2 = fmaf(watt[h+2], fmaf(-2.0f, r2, 1.0f), a2);
      a3 = fmaf(watt[h+3], fmaf(-2.0f, r3, 1.0f), a3);
    }
    float a = (a0 + a1) + (a2 + a3);
    // Reference f32 semantics: +10000.0f quantizes to 2^-10 buckets;
    // argmax/ties/sumexp operate on the quantized value.
    a = a + 10000.0f;
    // block reduce: max + first-argmax (wave level)
    float m = a; int ix = city;
    #pragma unroll
    for (int k = 1; k < 64; k <<= 1) {
      float om = __shfl_xor(m, k);
      int   oi = __shfl_xor(ix, k);
      if (om > m || (om == m && oi < ix)) { m = om; ix = oi; }
    }
    const int wv = tid >> 6;
    if ((tid & 63) == 0) { s_wm[wv] = m; s_wi[wv] = ix; }
    // ---- stage 3 (overlapped): next step's h @ W_hh.T partial ------------
    {
      const float* hs = s_h + hk * 8;
      float pa = 0.f;
      #pragma unroll
      for (int u = 0; u < 8; ++u) pa = fmaf(whh[u], hs[u], pa);
      s_scr[tid] = pa;
    }
    __syncthreads();
    m = s_wm[0]; ix = s_wi[0];
    #pragma unroll
    for (int w = 1; w < 4; ++w) {
      float om = s_wm[w]; int oi = s_wi[w];
      if (om > m || (om == m && oi < ix)) { m = om; ix = oi; }
    }
    if (city == ix) { s_wsel[0] = sx; s_wsel[1] = sy; }  // block winner coords
    float ee = __builtin_amdgcn_exp2f((a - m) * kLog2e);  // a-m exact
    #pragma unroll
    for (int k = 1; k < 64; k <<= 1) ee += __shfl_xor(ee, k);
    if ((tid & 63) == 0) s_we[wv] = ee;
    if (tid < 16) {   // finish h@W_hh.T 16-wide reduce, publish coherently
      float acc = 0.f;
      #pragma unroll
      for (int j = 0; j < 16; ++j) acc += s_scr[j * 16 + tid];
      cst(hhbuf + (((t + 1) & 1) * 8 + b) * 1024 + blk * 16 + tid, acc);
    }
    __syncthreads();
    if (tid == 0) {
      float St = (s_we[0] + s_we[1]) + (s_we[2] + s_we[3]);
      float* p = parts + (t & 1) * 2048 + b * 256 + blk * 8;
      cst(p + 0, m);
      cst(p + 1, __int_as_float(ix));
      cst(p + 2, St);
      cst(p + 3, s_wsel[0]);
      cst(p + 4, s_wsel[1]);
    }
    // ---- per-group barrier (leader-only, coherent, 4KB-padded counter) ---
    __syncthreads();
    target += 32;
    if (tid == 0) {
      // order wave-0's coherent stores (hhbuf, parts) before the signal
      asm volatile("s_waitcnt vmcnt(0)" ::: "memory");
      __hip_atomic_fetch_add(&bar[b * 1024], 1u, __ATOMIC_RELAXED,
                             __HIP_MEMORY_SCOPE_AGENT);
      while (__hip_atomic_load(&bar[b * 1024], __ATOMIC_RELAXED,
                               __HIP_MEMORY_SCOPE_AGENT) < target)
        __builtin_amdgcn_s_sleep(1);
    }
    __syncthreads();
  }
  // epilogue: outputs of the final step
  if (blk == 0 && tid < 32) {
    float M, St, sxw, syw; int IX;
    combine32(parts + ((steps - 1) & 1) * 2048 + b * 256, tid, M, IX, St,
              sxw, syw);
    if (tid == 0) {
      out[b * steps + (steps - 1)] = (float)IX;
      out[NB * steps + b * steps + (steps - 1)] =
          -__builtin_amdgcn_logf(St) * kLn2;
    }
  }
}

extern "C" void kernel_launch(void* const* d_in, const int* in_sizes, int n_in,
                              void* d_out, int out_size, void* d_ws, size_t ws_size,
                              hipStream_t stream) {
  // ws layout (4KB-padded to avoid IC false sharing across groups):
  //   [0, 32K)    barrier counters, bar[g*1024], zeroed each launch
  //   [32K, 48K)  softmax partials: phase*8KB + group*1KB + blk*32B
  //   [48K, 112K) h@W_hh.T buffers: (phase*8+group)*4KB
  hipMemsetAsync(d_ws, 0, 32768, stream);
  unsigned* bar   = (unsigned*)d_ws;
  float*    parts = (float*)((char*)d_ws + 32768);
  float*    hhb   = (float*)((char*)d_ws + 49152);
  drl4_kernel<<<dim3(256), dim3(256), 0, stream>>>(
      (const float*)d_in[0],  (const float*)d_in[1],
      (const float*)d_in[2],  (const float*)d_in[3],
      (const float*)d_in[4],  (const float*)d_in[5],
      (const float*)d_in[6],  (const float*)d_in[7],
      (const float*)d_in[8],  (const float*)d_in[9],
      (const float*)d_in[10], (const float*)d_in[11],
      (const float*)d_in[12], (const float*)d_in[13],
      (const float*)d_in[14], (const float*)d_in[15],
      (const float*)d_in[16], (const float*)d_in[17],
      (const float*)d_in[18], (const int*)d_in[19],
      (float*)d_out, bar, parts, hhb);
}

// Round 5
// 223.965 us; speedup vs baseline: 2.6568x; 1.1455x over previous
//
#include <hip/hip_runtime.h>
#include <hip/hip_bf16.h>

// DRL4Metro pointer-network decode, MI355X persistent kernel.
// B=8, S=8192, H=128, steps=20 (read from d_in[19]).
// Grid 256x256; 8 groups (one per batch) of 32 blocks.
//
// R5 sync design: NO barrier counter. Each block publishes ONE atomic 8-byte
// record per step:  lo32 = tag(5b)<<27 | (k+8192)<<13 | (8191-ix),  hi32 = S.
// aq = attn+10000.0f is quantized to 2^-10 buckets (exponent 13), so
// k=(int)((aq-10000)*1024) is EXACT and (max, first-idx) == single u32 max.
// Readers poll the 32 records of the previous step (tag == t, double-buffered
// slots; 0xAA poison gives tag 21, never matching tags 1..20, and the 2-slot
// overwrite argument makes in-run/cross-launch staleness impossible for
// steps <= 20). The poll IS the group barrier and carries the data.
// Winner coords come from read-only g_static (local L2), not the record.

#define SS 8192
#define HH 128
#define NB 8

constexpr float kLog2e  = 1.4426950408889634f;
constexpr float kLn2    = 0.6931471805599453f;
constexpr float kBucket = 9.765625e-4f;            // 2^-10
constexpr float kBL2e   = kLog2e * 9.765625e-4f;   // 2^-10 * log2e

__device__ __forceinline__ float fsig(float x) {
  return __builtin_amdgcn_rcpf(1.0f + __builtin_amdgcn_exp2f(-x * kLog2e));
}
__device__ __forceinline__ float ftanh(float x) {
  float z = __builtin_amdgcn_exp2f(x * (2.0f * kLog2e));
  return fmaf(-2.0f, __builtin_amdgcn_rcpf(z + 1.0f), 1.0f);
}

// Device-coherent (agent-scope, sc0 sc1) accessors — bypass per-XCD L2.
__device__ __forceinline__ float cld(const float* p) {
  return __hip_atomic_load(p, __ATOMIC_RELAXED, __HIP_MEMORY_SCOPE_AGENT);
}
__device__ __forceinline__ void cst(float* p, float v) {
  __hip_atomic_store(p, v, __ATOMIC_RELAXED, __HIP_MEMORY_SCOPE_AGENT);
}
__device__ __forceinline__ unsigned long long cld64(const unsigned long long* p) {
  return __hip_atomic_load(p, __ATOMIC_RELAXED, __HIP_MEMORY_SCOPE_AGENT);
}
__device__ __forceinline__ void cst64(unsigned long long* p, unsigned long long v) {
  __hip_atomic_store(p, v, __ATOMIC_RELAXED, __HIP_MEMORY_SCOPE_AGENT);
}

__global__ __launch_bounds__(256, 1)
void drl4_kernel(const float* __restrict__ g_static,
                 const float* __restrict__ g_dynamic,
                 const float* __restrict__ W_s,  const float* __restrict__ b_s,
                 const float* __restrict__ W_d,  const float* __restrict__ b_d,
                 const float* __restrict__ W_dec,const float* __restrict__ b_dec,
                 const float* __restrict__ W_ih, const float* __restrict__ W_hh,
                 const float* __restrict__ b_ih, const float* __restrict__ b_hh,
                 const float* __restrict__ W_ref,const float* __restrict__ b_ref,
                 const float* __restrict__ W_pd, const float* __restrict__ b_pd,
                 const float* __restrict__ W_q,  const float* __restrict__ b_q,
                 const float* __restrict__ W_att,const int* __restrict__ steps_p,
                 float* __restrict__ out,
                 unsigned long long* __restrict__ rec,
                 float* __restrict__ hhbuf) {
  const int tid = threadIdx.x;
  const int bid = blockIdx.x;
  const int b   = bid >> 5;   // batch / group id
  const int blk = bid & 31;   // block within group
  const int steps = *steps_p;

  __shared__ float4 s_pack[128];   // startup only: {A0,A1,C}*2log2e, W_att
  __shared__ float  s_ebias[128];  // W_ref@b_s + b_ref + W_pd@b_d + b_pd + b_q
  __shared__ float  s_gb[512];     // W_ih@b_dec + b_ih + b_hh
  __shared__ float  s_g1x[512];    // W_ih @ W_dec col0
  __shared__ float  s_g1y[512];    // W_ih @ W_dec col1
  __shared__ float  s_h[128];      // current LSTM hidden (this batch)
  __shared__ __align__(16) float s_qe[128];  // exp2((q+ebias)*2log2e)
  __shared__ float  s_scr[256];
  __shared__ unsigned s_wk[4];
  __shared__ float  s_we[4];

  // each thread owns exactly one city of this batch
  const int city = blk * 256 + tid;
  const float sx = g_static[(b * 2 + 0) * SS + city];
  const float sy = g_static[(b * 2 + 1) * SS + city];
  const float dd = g_dynamic[b * SS + city];

  // ---- persistent register fragments (loaded once) -----------------------
  // W_q: wave w, lane l -> row = w*32 + (l&31), half = l>>5.
  const int qrow  = (tid >> 6) * 32 + (tid & 31);
  const int qhalf = (tid >> 5) & 1;
  float wq[64];
  {
    const float* p = W_q + qrow * HH + qhalf * 64;
    #pragma unroll
    for (int j = 0; j < 64; j += 4) {
      float4 v = *(const float4*)(p + j);
      wq[j] = v.x; wq[j+1] = v.y; wq[j+2] = v.z; wq[j+3] = v.w;
    }
  }
  // W_hh fragment: block owns gate rows [blk*16, blk*16+16).
  const int ho = tid & 15, hk = tid >> 4;
  float whh[8];
  {
    const float* p = W_hh + (blk * 16 + ho) * HH + hk * 8;
    #pragma unroll
    for (int j = 0; j < 8; j += 4) {
      float4 v = *(const float4*)(p + j);
      whh[j] = v.x; whh[j+1] = v.y; whh[j+2] = v.z; whh[j+3] = v.w;
    }
  }

  // ---- one-time per-block precompute (collapsed linear algebra) ----------
  // Single pass over W_ih: gate bias (W_ih@b_dec + b_ih + b_hh) and the
  // collapsed input matrix W_ih@W_dec (2 cols) together.
  for (int g = tid; g < 512; g += 256) {
    const float* wr = W_ih + g * HH;
    float acc = b_ih[g] + b_hh[g];
    float ax = 0.f, ay = 0.f;
    for (int k = 0; k < HH; ++k) {
      float w = wr[k];
      acc = fmaf(w, b_dec[k],      acc);
      ax  = fmaf(w, W_dec[2*k],    ax);
      ay  = fmaf(w, W_dec[2*k+1],  ay);
    }
    s_gb[g] = acc; s_g1x[g] = ax; s_g1y[g] = ay;
  }
  if (tid < 128) {
    float a0 = 0.f, a1 = 0.f, c0 = 0.f, e1 = 0.f, e2 = 0.f;
    const float* wr = W_ref + tid * HH;
    const float* wp = W_pd  + tid * HH;
    for (int k = 0; k < HH; ++k) {
      float w = wr[k], v = wp[k];
      a0 = fmaf(w, W_s[2 * k],     a0);
      a1 = fmaf(w, W_s[2 * k + 1], a1);
      e1 = fmaf(w, b_s[k],         e1);
      c0 = fmaf(v, W_d[k],         c0);
      e2 = fmaf(v, b_d[k],         e2);
    }
    const float sc = 2.0f * kLog2e;   // pre-fold tanh's 2*log2e scaling
    s_pack[tid]  = make_float4(a0 * sc, a1 * sc, c0 * sc, W_att[tid]);
    s_ebias[tid] = e1 + e2 + b_ref[tid] + b_pd[tid] + b_q[tid];
  }
  float cstate = 0.0f;   // LSTM cell state for (b, tid) — threads tid<128
  __syncthreads();

  // ---- per-thread step-invariant attention state -------------------------
  float zb[128], watt[128];
  #pragma unroll
  for (int h = 0; h < 128; ++h) {
    float4 p = s_pack[h];
    zb[h]   = __builtin_amdgcn_exp2f(fmaf(p.x, sx, fmaf(p.y, sy, p.z * dd)));
    watt[h] = p.w;
  }

  float selx = 0.f, sely = 0.f;
  for (int t = 0; t < steps; ++t) {
    // ---- stage 1: poll prev-step records (THE barrier) + consume ---------
    float hp0 = 0.f, hp1 = 0.f, hp2 = 0.f, hp3 = 0.f;
    if (t > 0) {
      if (tid < 128) {   // waves 0,1 poll; waves 2,3 wait at the LSTM sync
        const unsigned long long* rp =
            rec + ((t - 1) & 1) * 512 + b * 64 + (tid & 31);
        unsigned long long rv;
        const unsigned expect = (unsigned)t;   // tag of records from step t-1
        for (;;) {
          rv = cld64(rp);
          if (__ballot(((unsigned)rv >> 27) == expect) == ~0ull) break;
          __builtin_amdgcn_s_sleep(1);
        }
        unsigned wmax = (unsigned)rv & 0x07FFFFFFu;
        #pragma unroll
        for (int k = 1; k < 64; k <<= 1) {
          unsigned o = __shfl_xor(wmax, k);
          wmax = wmax > o ? wmax : o;
        }
        const int ix = 8191 - (int)(wmax & 0x1FFFu);
        // coherent hhbuf loads (safe: publishers drained them before tagging)
        const float* hp = hhbuf + ((t & 1) * 8 + b) * 512 + tid;
        hp0 = cld(hp);       hp1 = cld(hp + 128);
        hp2 = cld(hp + 256); hp3 = cld(hp + 384);
        // winner coords from read-only input (local L2, cheap broadcast)
        selx = g_static[(b * 2 + 0) * SS + ix];
        sely = g_static[(b * 2 + 1) * SS + ix];
        if (blk == 0 && tid < 64) {  // wave0 of group leader: outputs t-1
          int   kb = (int)(((unsigned)rv >> 13) & 0x3FFFu) - 8192;
          int   K  = (int)((wmax >> 13) & 0x3FFFu) - 8192;
          float Sb = __uint_as_float((unsigned)(rv >> 32));
          float term = Sb * __builtin_amdgcn_exp2f((float)(kb - K) * kBL2e);
          #pragma unroll
          for (int k = 1; k < 32; k <<= 1) term += __shfl_xor(term, k, 32);
          if (tid == 0) {
            out[b * steps + (t - 1)] = (float)ix;
            out[NB * steps + b * steps + (t - 1)] =
                -__builtin_amdgcn_logf(term) * kLn2;
          }
        }
      }
    }
    // ---- stage 2: LSTM cell (threads tid<128) ----------------------------
    if (tid < 128) {
      float gi, gf, gg, go;
      if (t == 0) {   // dec_in = 0, h = 0 → gates are just the bias term
        gi = s_gb[tid];       gf = s_gb[tid + 128];
        gg = s_gb[tid + 256]; go = s_gb[tid + 384];
      } else {
        gi = fmaf(selx, s_g1x[tid],     fmaf(sely, s_g1y[tid],     s_gb[tid]     + hp0));
        gf = fmaf(selx, s_g1x[tid+128], fmaf(sely, s_g1y[tid+128], s_gb[tid+128] + hp1));
        gg = fmaf(selx, s_g1x[tid+256], fmaf(sely, s_g1y[tid+256], s_gb[tid+256] + hp2));
        go = fmaf(selx, s_g1x[tid+384], fmaf(sely, s_g1y[tid+384], s_gb[tid+384] + hp3));
      }
      cstate  = fmaf(fsig(gf), cstate, fsig(gi) * ftanh(gg));
      s_h[tid] = fsig(go) * ftanh(cstate);
    }
    __syncthreads();
    // ---- stage 2b: q = h @ W_q.T (shfl-combined halves) ------------------
    {
      const float* hs = s_h + (qhalf << 6);
      float qa = 0.f;
      #pragma unroll
      for (int u = 0; u < 64; ++u) qa = fmaf(wq[u], hs[u], qa);
      float qo = __shfl_xor(qa, 32);
      if (qhalf == 0) {
        float qe = (qa + qo + s_ebias[qrow]) * (2.0f * kLog2e);
        s_qe[qrow] = __builtin_amdgcn_exp2f(qe);
      }
    }
    // ---- stage 3: next step's h @ W_hh.T partial (early, to hide drain) --
    {
      const float* hs2 = s_h + hk * 8;
      float pa = 0.f;
      #pragma unroll
      for (int u = 0; u < 8; ++u) pa = fmaf(whh[u], hs2[u], pa);
      s_scr[tid] = pa;
    }
    __syncthreads();
    if (tid < 16) {   // publish hh partial; drains during attention below
      float acc = 0.f;
      #pragma unroll
      for (int j = 0; j < 16; ++j) acc += s_scr[j * 16 + tid];
      cst(hhbuf + ((((t + 1) & 1)) * 8 + b) * 512 + blk * 16 + tid, acc);
    }
    // ---- stage 4: attention (bit-identical to R4) ------------------------
    float a0 = 0.f, a1 = 0.f, a2 = 0.f, a3 = 0.f;
    #pragma unroll
    for (int h = 0; h < 128; h += 4) {
      float4 zq = *(const float4*)(s_qe + h);
      float z0 = zb[h+0] * zq.x, z1 = zb[h+1] * zq.y;
      float z2 = zb[h+2] * zq.z, z3 = zb[h+3] * zq.w;
      float r0 = __builtin_amdgcn_rcpf(z0 + 1.0f);
      float r1 = __builtin_amdgcn_rcpf(z1 + 1.0f);
      float r2 = __builtin_amdgcn_rcpf(z2 + 1.0f);
      float r3 = __builtin_amdgcn_rcpf(z3 + 1.0f);
      a0 = fmaf(watt[h+0], fmaf(-2.0f, r0, 1.0f), a0);
      a1 = fmaf(watt[h+1], fmaf(-2.0f, r1, 1.0f), a1);
      a2 = fmaf(watt[h+2], fmaf(-2.0f, r2, 1.0f), a2);
      a3 = fmaf(watt[h+3], fmaf(-2.0f, r3, 1.0f), a3);
    }
    float aq = ((a0 + a1) + (a2 + a3)) + 10000.0f;   // 2^-10-bucket quantized
    int kk = (int)((aq - 10000.0f) * 1024.0f);       // exact bucket index
    kk = kk < -8192 ? -8192 : (kk > 8191 ? 8191 : kk);
    unsigned key = ((unsigned)(kk + 8192) << 13) | (unsigned)(8191 - city);
    unsigned wmax = key;
    #pragma unroll
    for (int k = 1; k < 64; k <<= 1) {
      unsigned o = __shfl_xor(wmax, k);
      wmax = wmax > o ? wmax : o;
    }
    const int wv = tid >> 6;
    if ((tid & 63) == 0) s_wk[wv] = wmax;
    __syncthreads();
    unsigned bkey = s_wk[0];
    bkey = bkey > s_wk[1] ? bkey : s_wk[1];
    bkey = bkey > s_wk[2] ? bkey : s_wk[2];
    bkey = bkey > s_wk[3] ? bkey : s_wk[3];
    // m reconstructs bit-exactly: aq-values are 10000 + k*2^-10
    float m = fmaf((float)((int)((bkey >> 13) & 0x3FFFu) - 8192), kBucket,
                   10000.0f);
    float ee = __builtin_amdgcn_exp2f((aq - m) * kLog2e);   // exact diff
    #pragma unroll
    for (int k = 1; k < 64; k <<= 1) ee += __shfl_xor(ee, k);
    if ((tid & 63) == 0) s_we[wv] = ee;
    __syncthreads();
    if (tid == 0) {
      float St = (s_we[0] + s_we[1]) + (s_we[2] + s_we[3]);
      unsigned pk = ((unsigned)(t + 1) << 27) | bkey;
      unsigned long long rv =
          ((unsigned long long)__float_as_uint(St) << 32) | pk;
      // drain wave0's hh cst (and own coherent loads) before tagging
      asm volatile("s_waitcnt vmcnt(0)" ::: "memory");
      cst64(rec + (t & 1) * 512 + b * 64 + blk, rv);
    }
    // no end-of-step barrier: next iteration's poll is the barrier
  }
  // epilogue: outputs of the final step (group-leader wave0)
  if (blk == 0 && tid < 64) {
    const unsigned long long* rp =
        rec + ((steps - 1) & 1) * 512 + b * 64 + (tid & 31);
    unsigned long long rv;
    const unsigned expect = (unsigned)steps;
    for (;;) {
      rv = cld64(rp);
      if (__ballot(((unsigned)rv >> 27) == expect) == ~0ull) break;
      __builtin_amdgcn_s_sleep(1);
    }
    unsigned wmax = (unsigned)rv & 0x07FFFFFFu;
    #pragma unroll
    for (int k = 1; k < 64; k <<= 1) {
      unsigned o = __shfl_xor(wmax, k);
      wmax = wmax > o ? wmax : o;
    }
    int   ix = 8191 - (int)(wmax & 0x1FFFu);
    int   kb = (int)(((unsigned)rv >> 13) & 0x3FFFu) - 8192;
    int   K  = (int)((wmax >> 13) & 0x3FFFu) - 8192;
    float Sb = __uint_as_float((unsigned)(rv >> 32));
    float term = Sb * __builtin_amdgcn_exp2f((float)(kb - K) * kBL2e);
    #pragma unroll
    for (int k = 1; k < 32; k <<= 1) term += __shfl_xor(term, k, 32);
    if (tid == 0) {
      out[b * steps + (steps - 1)] = (float)ix;
      out[NB * steps + b * steps + (steps - 1)] =
          -__builtin_amdgcn_logf(term) * kLn2;
    }
  }
}

extern "C" void kernel_launch(void* const* d_in, const int* in_sizes, int n_in,
                              void* d_out, int out_size, void* d_ws, size_t ws_size,
                              hipStream_t stream) {
  // ws layout (self-initializing — no memset needed; 0xAA poison gives
  // record tag 21 which never matches expected tags 1..20):
  //   [0, 8K)    records: u64 rec[2 phases][8 groups * 64] (group stride 512B)
  //   [8K, 40K)  h@W_hh.T partials: float hh[2][8][512]
  unsigned long long* rec = (unsigned long long*)d_ws;
  float* hhb = (float*)((char*)d_ws + 8192);
  drl4_kernel<<<dim3(256), dim3(256), 0, stream>>>(
      (const float*)d_in[0],  (const float*)d_in[1],
      (const float*)d_in[2],  (const float*)d_in[3],
      (const float*)d_in[4],  (const float*)d_in[5],
      (const float*)d_in[6],  (const float*)d_in[7],
      (const float*)d_in[8],  (const float*)d_in[9],
      (const float*)d_in[10], (const float*)d_in[11],
      (const float*)d_in[12], (const float*)d_in[13],
      (const float*)d_in[14], (const float*)d_in[15],
      (const float*)d_in[16], (const float*)d_in[17],
      (const float*)d_in[18], (const int*)d_in[19],
      (float*)d_out, rec, hhb);
}

// Round 6
// 196.960 us; speedup vs baseline: 3.0210x; 1.1371x over previous
//
#include <hip/hip_runtime.h>
#include <hip/hip_bf16.h>

// DRL4Metro pointer-network decode, MI355X persistent kernel.
// B=8, S=8192, H=128, steps=20 (read from d_in[19]).
// Grid 256x256; 8 groups (one per batch) of 32 blocks.
//
// R6 sync design: ALL cross-block data is self-tagged 8-byte records at
// agent scope (sc0 sc1, IC-coherent). Per block per step:
//   krec  u64 {tag=t+1 (hi32) | bkey (lo32)}   -- published right after the
//          key max; bkey = (k+8192)<<13 | (8191-ix_local), k = exact 2^-10
//          bucket index of attn+10000.0f. Consumers' poll of the 32 krecs
//          IS the group barrier AND delivers the argmax.
//   hhrec u64 {tag=t+1 | h@W_hh row value}, 16 rows/block -- polled in the
//          SAME spin loop as krec, so LSTM inputs arrive with the barrier.
//   frec  u64 {S (hi32) | tag(5)<<27|(k+8192)<<13|(8191-ix)} -- sumexp path,
//          polled only by blk0's wave 2 (output writer), off the hot path.
// No fences, no vmcnt drains: every datum is self-validating. 0xAA poison
// gives tags 0xAAAAAAAA / 21, never matching 1..20; slot reuse is gated by a
// full krec generation (slowest consumer publishes only after reading).

#define SS 8192
#define HH 128
#define NB 8

constexpr float kLog2e  = 1.4426950408889634f;
constexpr float kLn2    = 0.6931471805599453f;
constexpr float kBucket = 9.765625e-4f;            // 2^-10
constexpr float kBL2e   = kLog2e * 9.765625e-4f;   // 2^-10 * log2e

__device__ __forceinline__ float fsig(float x) {
  return __builtin_amdgcn_rcpf(1.0f + __builtin_amdgcn_exp2f(-x * kLog2e));
}
__device__ __forceinline__ float ftanh(float x) {
  float z = __builtin_amdgcn_exp2f(x * (2.0f * kLog2e));
  return fmaf(-2.0f, __builtin_amdgcn_rcpf(z + 1.0f), 1.0f);
}

__device__ __forceinline__ unsigned long long cld64(const unsigned long long* p) {
  return __hip_atomic_load(p, __ATOMIC_RELAXED, __HIP_MEMORY_SCOPE_AGENT);
}
__device__ __forceinline__ void cst64(unsigned long long* p, unsigned long long v) {
  __hip_atomic_store(p, v, __ATOMIC_RELAXED, __HIP_MEMORY_SCOPE_AGENT);
}

__global__ __launch_bounds__(256, 1)
void drl4_kernel(const float* __restrict__ g_static,
                 const float* __restrict__ g_dynamic,
                 const float* __restrict__ W_s,  const float* __restrict__ b_s,
                 const float* __restrict__ W_d,  const float* __restrict__ b_d,
                 const float* __restrict__ W_dec,const float* __restrict__ b_dec,
                 const float* __restrict__ W_ih, const float* __restrict__ W_hh,
                 const float* __restrict__ b_ih, const float* __restrict__ b_hh,
                 const float* __restrict__ W_ref,const float* __restrict__ b_ref,
                 const float* __restrict__ W_pd, const float* __restrict__ b_pd,
                 const float* __restrict__ W_q,  const float* __restrict__ b_q,
                 const float* __restrict__ W_att,const int* __restrict__ steps_p,
                 float* __restrict__ out,
                 unsigned long long* __restrict__ krec,
                 unsigned long long* __restrict__ frec,
                 unsigned long long* __restrict__ hhrec) {
  const int tid = threadIdx.x;
  const int bid = blockIdx.x;
  const int b   = bid >> 5;   // batch / group id
  const int blk = bid & 31;   // block within group
  const int steps = *steps_p;

  __shared__ float4 s_pack[128];   // startup only: {A0,A1,C}*2log2e, W_att
  __shared__ float  s_ebias[128];  // W_ref@b_s + b_ref + W_pd@b_d + b_pd + b_q
  __shared__ float  s_gb[512];     // W_ih@b_dec + b_ih + b_hh
  __shared__ float  s_g1x[512];    // W_ih @ W_dec col0
  __shared__ float  s_g1y[512];    // W_ih @ W_dec col1
  __shared__ float  s_h[128];      // current LSTM hidden (this batch)
  __shared__ __align__(16) float s_qe[128];  // exp2((q+ebias)*2log2e)
  __shared__ float  s_scr[256];
  __shared__ unsigned s_wk[4];
  __shared__ float  s_we[4];

  // each thread owns exactly one city of this batch
  const int city = blk * 256 + tid;
  const float sx = g_static[(b * 2 + 0) * SS + city];
  const float sy = g_static[(b * 2 + 1) * SS + city];
  const float dd = g_dynamic[b * SS + city];

  // ---- persistent register fragments (loaded once) -----------------------
  const int qrow  = (tid >> 6) * 32 + (tid & 31);
  const int qhalf = (tid >> 5) & 1;
  float wq[64];
  {
    const float* p = W_q + qrow * HH + qhalf * 64;
    #pragma unroll
    for (int j = 0; j < 64; j += 4) {
      float4 v = *(const float4*)(p + j);
      wq[j] = v.x; wq[j+1] = v.y; wq[j+2] = v.z; wq[j+3] = v.w;
    }
  }
  // W_hh fragment: block owns gate rows [blk*16, blk*16+16).
  const int ho = tid & 15, hk = tid >> 4;
  float whh[8];
  {
    const float* p = W_hh + (blk * 16 + ho) * HH + hk * 8;
    #pragma unroll
    for (int j = 0; j < 8; j += 4) {
      float4 v = *(const float4*)(p + j);
      whh[j] = v.x; whh[j+1] = v.y; whh[j+2] = v.z; whh[j+3] = v.w;
    }
  }

  // ---- one-time per-block precompute (collapsed linear algebra) ----------
  for (int g = tid; g < 512; g += 256) {
    const float* wr = W_ih + g * HH;
    float acc = b_ih[g] + b_hh[g];
    float ax = 0.f, ay = 0.f;
    for (int k = 0; k < HH; ++k) {
      float w = wr[k];
      acc = fmaf(w, b_dec[k],      acc);
      ax  = fmaf(w, W_dec[2*k],    ax);
      ay  = fmaf(w, W_dec[2*k+1],  ay);
    }
    s_gb[g] = acc; s_g1x[g] = ax; s_g1y[g] = ay;
  }
  if (tid < 128) {
    float a0 = 0.f, a1 = 0.f, c0 = 0.f, e1 = 0.f, e2 = 0.f;
    const float* wr = W_ref + tid * HH;
    const float* wp = W_pd  + tid * HH;
    for (int k = 0; k < HH; ++k) {
      float w = wr[k], v = wp[k];
      a0 = fmaf(w, W_s[2 * k],     a0);
      a1 = fmaf(w, W_s[2 * k + 1], a1);
      e1 = fmaf(w, b_s[k],         e1);
      c0 = fmaf(v, W_d[k],         c0);
      e2 = fmaf(v, b_d[k],         e2);
    }
    const float sc = 2.0f * kLog2e;   // pre-fold tanh's 2*log2e scaling
    s_pack[tid]  = make_float4(a0 * sc, a1 * sc, c0 * sc, W_att[tid]);
    s_ebias[tid] = e1 + e2 + b_ref[tid] + b_pd[tid] + b_q[tid];
  }
  float cstate = 0.0f;   // LSTM cell state for (b, tid) — threads tid<128
  __syncthreads();

  // ---- per-thread step-invariant attention state -------------------------
  float zb[128], watt[128];
  #pragma unroll
  for (int h = 0; h < 128; ++h) {
    float4 p = s_pack[h];
    zb[h]   = __builtin_amdgcn_exp2f(fmaf(p.x, sx, fmaf(p.y, sy, p.z * dd)));
    watt[h] = p.w;
  }

  for (int t = 0; t < steps; ++t) {
    // ---- stage 1: single spin delivers barrier + argmax + LSTM inputs ----
    float hp0 = 0.f, hp1 = 0.f, hp2 = 0.f, hp3 = 0.f;
    float selx = 0.f, sely = 0.f;
    if (t > 0) {
      if (tid < 128) {   // waves 0,1: the hot path
        const unsigned expect = (unsigned)t;
        const unsigned long long* kp =
            krec + ((t - 1) & 1) * 512 + b * 64 + (tid & 31);
        const unsigned long long* hp =
            hhrec + (t & 1) * 4096 + b * 512 + tid;
        unsigned long long kv, h0, h1, h2, h3;
        for (;;) {
          kv = cld64(kp);
          h0 = cld64(hp);       h1 = cld64(hp + 128);
          h2 = cld64(hp + 256); h3 = cld64(hp + 384);
          if ((unsigned)(kv >> 32) == expect && (unsigned)(h0 >> 32) == expect &&
              (unsigned)(h1 >> 32) == expect && (unsigned)(h2 >> 32) == expect &&
              (unsigned)(h3 >> 32) == expect) break;
          __builtin_amdgcn_s_sleep(1);
        }
        unsigned wmax = (unsigned)kv;
        #pragma unroll
        for (int k = 1; k < 64; k <<= 1) {
          unsigned o = __shfl_xor(wmax, k);
          wmax = wmax > o ? wmax : o;
        }
        const int ix = 8191 - (int)(wmax & 0x1FFFu);
        hp0 = __uint_as_float((unsigned)h0);
        hp1 = __uint_as_float((unsigned)h1);
        hp2 = __uint_as_float((unsigned)h2);
        hp3 = __uint_as_float((unsigned)h3);
        selx = g_static[(b * 2 + 0) * SS + ix];   // broadcast, L1/L2-local
        sely = g_static[(b * 2 + 1) * SS + ix];
      } else if (blk == 0 && tid < 192) {
        // wave 2 of group leader: frec poll + outputs for step t-1
        const unsigned expect = (unsigned)t;   // 5-bit tag
        const unsigned long long* fp =
            frec + ((t - 1) & 1) * 512 + b * 64 + (tid & 31);
        unsigned long long rv;
        for (;;) {
          rv = cld64(fp);
          if (((unsigned)rv >> 27) == expect) break;
          __builtin_amdgcn_s_sleep(1);
        }
        unsigned wmax = (unsigned)rv & 0x07FFFFFFu;
        #pragma unroll
        for (int k = 1; k < 64; k <<= 1) {
          unsigned o = __shfl_xor(wmax, k);
          wmax = wmax > o ? wmax : o;
        }
        int   ixf = 8191 - (int)(wmax & 0x1FFFu);
        int   kb  = (int)(((unsigned)rv >> 13) & 0x3FFFu) - 8192;
        int   K   = (int)((wmax >> 13) & 0x3FFFu) - 8192;
        float Sb  = __uint_as_float((unsigned)(rv >> 32));
        float term = Sb * __builtin_amdgcn_exp2f((float)(kb - K) * kBL2e);
        #pragma unroll
        for (int k = 1; k < 32; k <<= 1) term += __shfl_xor(term, k, 32);
        if (tid == 128) {
          out[b * steps + (t - 1)] = (float)ixf;
          out[NB * steps + b * steps + (t - 1)] =
              -__builtin_amdgcn_logf(term) * kLn2;
        }
      }
    }
    // ---- stage 2: LSTM cell (threads tid<128) ----------------------------
    if (tid < 128) {
      float gi, gf, gg, go;
      if (t == 0) {   // dec_in = 0, h = 0 → gates are just the bias term
        gi = s_gb[tid];       gf = s_gb[tid + 128];
        gg = s_gb[tid + 256]; go = s_gb[tid + 384];
      } else {
        gi = fmaf(selx, s_g1x[tid],     fmaf(sely, s_g1y[tid],     s_gb[tid]     + hp0));
        gf = fmaf(selx, s_g1x[tid+128], fmaf(sely, s_g1y[tid+128], s_gb[tid+128] + hp1));
        gg = fmaf(selx, s_g1x[tid+256], fmaf(sely, s_g1y[tid+256], s_gb[tid+256] + hp2));
        go = fmaf(selx, s_g1x[tid+384], fmaf(sely, s_g1y[tid+384], s_gb[tid+384] + hp3));
      }
      cstate  = fmaf(fsig(gf), cstate, fsig(gi) * ftanh(gg));
      s_h[tid] = fsig(go) * ftanh(cstate);
    }
    __syncthreads();
    // ---- stage 2b: q = h @ W_q.T (shfl-combined halves) ------------------
    {
      const float* hs = s_h + (qhalf << 6);
      float qa = 0.f;
      #pragma unroll
      for (int u = 0; u < 64; ++u) qa = fmaf(wq[u], hs[u], qa);
      float qo = __shfl_xor(qa, 32);
      if (qhalf == 0) {
        float qe = (qa + qo + s_ebias[qrow]) * (2.0f * kLog2e);
        s_qe[qrow] = __builtin_amdgcn_exp2f(qe);
      }
    }
    // ---- stage 3: next step's h @ W_hh.T partial -------------------------
    {
      const float* hs2 = s_h + hk * 8;
      float pa = 0.f;
      #pragma unroll
      for (int u = 0; u < 8; ++u) pa = fmaf(whh[u], hs2[u], pa);
      s_scr[tid] = pa;
    }
    __syncthreads();
    if (tid < 16) {   // publish self-tagged hh rows; land during attention
      float acc = 0.f;
      #pragma unroll
      for (int j = 0; j < 16; ++j) acc += s_scr[j * 16 + tid];
      cst64(hhrec + ((t + 1) & 1) * 4096 + b * 512 + blk * 16 + tid,
            ((unsigned long long)(unsigned)(t + 1) << 32) |
                __float_as_uint(acc));
    }
    // ---- stage 4: attention (bit-identical arithmetic) -------------------
    float a0 = 0.f, a1 = 0.f, a2 = 0.f, a3 = 0.f;
    #pragma unroll
    for (int h = 0; h < 128; h += 4) {
      float4 zq = *(const float4*)(s_qe + h);
      float z0 = zb[h+0] * zq.x, z1 = zb[h+1] * zq.y;
      float z2 = zb[h+2] * zq.z, z3 = zb[h+3] * zq.w;
      float r0 = __builtin_amdgcn_rcpf(z0 + 1.0f);
      float r1 = __builtin_amdgcn_rcpf(z1 + 1.0f);
      float r2 = __builtin_amdgcn_rcpf(z2 + 1.0f);
      float r3 = __builtin_amdgcn_rcpf(z3 + 1.0f);
      a0 = fmaf(watt[h+0], fmaf(-2.0f, r0, 1.0f), a0);
      a1 = fmaf(watt[h+1], fmaf(-2.0f, r1, 1.0f), a1);
      a2 = fmaf(watt[h+2], fmaf(-2.0f, r2, 1.0f), a2);
      a3 = fmaf(watt[h+3], fmaf(-2.0f, r3, 1.0f), a3);
    }
    float aq = ((a0 + a1) + (a2 + a3)) + 10000.0f;   // 2^-10-bucket quantized
    int kk = (int)((aq - 10000.0f) * 1024.0f);       // exact bucket index
    kk = kk < -8192 ? -8192 : (kk > 8191 ? 8191 : kk);
    unsigned key = ((unsigned)(kk + 8192) << 13) | (unsigned)(8191 - city);
    unsigned wmax = key;
    #pragma unroll
    for (int k = 1; k < 64; k <<= 1) {
      unsigned o = __shfl_xor(wmax, k);
      wmax = wmax > o ? wmax : o;
    }
    const int wv = tid >> 6;
    if ((tid & 63) == 0) s_wk[wv] = wmax;
    __syncthreads();
    unsigned bkey = s_wk[0];
    bkey = bkey > s_wk[1] ? bkey : s_wk[1];
    bkey = bkey > s_wk[2] ? bkey : s_wk[2];
    bkey = bkey > s_wk[3] ? bkey : s_wk[3];
    if (tid == 0)   // EARLY publish: consumers unblock on this
      cst64(krec + (t & 1) * 512 + b * 64 + blk,
            ((unsigned long long)(unsigned)(t + 1) << 32) | bkey);
    // ---- sumexp path (feeds frec only; off the group critical path) ------
    float m = fmaf((float)((int)((bkey >> 13) & 0x3FFFu) - 8192), kBucket,
                   10000.0f);
    float ee = __builtin_amdgcn_exp2f((aq - m) * kLog2e);   // exact diff
    #pragma unroll
    for (int k = 1; k < 64; k <<= 1) ee += __shfl_xor(ee, k);
    if ((tid & 63) == 0) s_we[wv] = ee;
    __syncthreads();
    if (tid == 0) {
      float St = (s_we[0] + s_we[1]) + (s_we[2] + s_we[3]);
      unsigned pk = ((unsigned)(t + 1) << 27) | bkey;
      cst64(frec + (t & 1) * 512 + b * 64 + blk,
            ((unsigned long long)__float_as_uint(St) << 32) | pk);
    }
    // no end-of-step barrier: next iteration's spin is the barrier
  }
  // epilogue: outputs of the final step (group leader, wave 0)
  if (blk == 0 && tid < 64) {
    const unsigned long long* fp =
        frec + ((steps - 1) & 1) * 512 + b * 64 + (tid & 31);
    unsigned long long rv;
    const unsigned expect = (unsigned)steps;
    for (;;) {
      rv = cld64(fp);
      if (((unsigned)rv >> 27) == expect) break;
      __builtin_amdgcn_s_sleep(1);
    }
    unsigned wmax = (unsigned)rv & 0x07FFFFFFu;
    #pragma unroll
    for (int k = 1; k < 64; k <<= 1) {
      unsigned o = __shfl_xor(wmax, k);
      wmax = wmax > o ? wmax : o;
    }
    int   ix = 8191 - (int)(wmax & 0x1FFFu);
    int   kb = (int)(((unsigned)rv >> 13) & 0x3FFFu) - 8192;
    int   K  = (int)((wmax >> 13) & 0x3FFFu) - 8192;
    float Sb = __uint_as_float((unsigned)(rv >> 32));
    float term = Sb * __builtin_amdgcn_exp2f((float)(kb - K) * kBL2e);
    #pragma unroll
    for (int k = 1; k < 32; k <<= 1) term += __shfl_xor(term, k, 32);
    if (tid == 0) {
      out[b * steps + (steps - 1)] = (float)ix;
      out[NB * steps + b * steps + (steps - 1)] =
          -__builtin_amdgcn_logf(term) * kLn2;
    }
  }
}

extern "C" void kernel_launch(void* const* d_in, const int* in_sizes, int n_in,
                              void* d_out, int out_size, void* d_ws, size_t ws_size,
                              hipStream_t stream) {
  // ws layout (self-initializing; no memset — all records self-tagged):
  //   [0, 8K)    krec : u64[2][8*64]   (group stride 512 B)
  //   [8K, 16K)  frec : u64[2][8*64]
  //   [16K, 80K) hhrec: u64[2][8*512]  (group stride 4 KB)
  unsigned long long* krec = (unsigned long long*)d_ws;
  unsigned long long* frec = (unsigned long long*)((char*)d_ws + 8192);
  unsigned long long* hhrec = (unsigned long long*)((char*)d_ws + 16384);
  drl4_kernel<<<dim3(256), dim3(256), 0, stream>>>(
      (const float*)d_in[0],  (const float*)d_in[1],
      (const float*)d_in[2],  (const float*)d_in[3],
      (const float*)d_in[4],  (const float*)d_in[5],
      (const float*)d_in[6],  (const float*)d_in[7],
      (const float*)d_in[8],  (const float*)d_in[9],
      (const float*)d_in[10], (const float*)d_in[11],
      (const float*)d_in[12], (const float*)d_in[13],
      (const float*)d_in[14], (const float*)d_in[15],
      (const float*)d_in[16], (const float*)d_in[17],
      (const float*)d_in[18], (const int*)d_in[19],
      (float*)d_out, krec, frec, hhrec);
}